// Round 1
// baseline (2341.966 us; speedup 1.0000x reference)
//
#include <hip/hip_runtime.h>
#include <math.h>

// MultiViewAggregation — fp32 reference-correct fused kernel.
// Shapes: P=16384 pixels, NV=8 views, SG=12, D=96, PH=64, HD=32, MH=256, FH=128.

#define NPIX 16384
#define NV 8
#define SGN 12

struct Params {
  const float* rgb; const float* fm; const float* view_dir; const float* proj_err;
  const float* normal; const float* DL;
  const float* pbr_ln_g; const float* pbr_ln_b;
  const float* pbr_w1; const float* pbr_b1; const float* pbr_w2; const float* pbr_b2;
  const float* pbr_w3; const float* pbr_b3; const float* pbr_w4; const float* pbr_b4;
  const float* tv1_ln_g; const float* tv1_ln_b; const float* tv1_w;
  const float* to1_w; const float* to1_b;
  const float* n1_ln_g; const float* n1_ln_b; const float* n1_w1; const float* n1_b1;
  const float* n1_w2; const float* n1_b2;
  const float* tv2_ln_g; const float* tv2_ln_b; const float* tv2_w;
  const float* to2_w; const float* to2_b;
  const float* n2_ln_g; const float* n2_ln_b; const float* n2_w1; const float* n2_b1;
  const float* n2_w2; const float* n2_b2;
  const float* brdf_ln_g; const float* brdf_ln_b; const float* brdf_w1; const float* brdf_b1;
  const float* brdf_w2; const float* brdf_b2;
  float* out;
};

// ---- LDS layout (floats) ----
// Union region U (phase A weights+y  /  phase B xln+hidden):
constexpr int A_W1  = 0;            // 7*64   = 448
constexpr int A_W2  = 448;          // 64*64  = 4096
constexpr int A_W3  = 4544;         // 64*64  = 4096
constexpr int A_Y   = 8640;         // 16 instances * stride 68 = 1088
constexpr int U_END = 9728;
constexpr int B_XLN = 0;            // 8 rows * stride 100 = 800
constexpr int B_H   = 800;          // 8 rows * stride 260 = 2080
// Persistent region:
constexpr int SM_FEAT = U_END;          // 8*32 = 256  (pbr_feature)
constexpr int SM_XIN  = SM_FEAT + 256;  // 8*96 = 768
constexpr int SM_XCUR = SM_XIN + 768;   // 8*96 = 768
constexpr int SM_V    = SM_XCUR + 768;  // 8*32 = 256
constexpr int SM_MEAN = SM_V + 256;     // 32
constexpr int SM_VAR  = SM_MEAN + 32;   // 32
constexpr int SM_XS   = SM_VAR + 32;    // 96
constexpr int SM_XSLN = SM_XS + 96;     // 96
constexpr int SM_WGT  = SM_XSLN + 96;   // 16 (raw[0..7], normalized[8..15])
constexpr int SM_TOT  = SM_WGT + 16;    // 12048 floats = 48192 B -> 3 blocks/CU

__device__ __forceinline__ float elu_f(float x){ return x > 0.f ? x : expm1f(x); }
__device__ __forceinline__ float gelu_f(float x){ return 0.5f*x*(1.f + erff(x*0.70710678118654752f)); }

// Hidden 64->64 layer for one instance-group: lane computes 4 cols (c0=4*l16).
__device__ __forceinline__ float4 hidden64(const float* __restrict__ yrow,
                                           const float* __restrict__ Ws,
                                           const float* __restrict__ bg, int l16)
{
  const float4* Wv = (const float4*)Ws;
  float4 acc = ((const float4*)bg)[l16];
  #pragma unroll 8
  for (int k = 0; k < 64; k += 4){
    float4 yv = *(const float4*)(yrow + k);
    float4 w0 = Wv[(k+0)*16 + l16];
    acc.x = fmaf(yv.x, w0.x, acc.x); acc.y = fmaf(yv.x, w0.y, acc.y);
    acc.z = fmaf(yv.x, w0.z, acc.z); acc.w = fmaf(yv.x, w0.w, acc.w);
    float4 w1 = Wv[(k+1)*16 + l16];
    acc.x = fmaf(yv.y, w1.x, acc.x); acc.y = fmaf(yv.y, w1.y, acc.y);
    acc.z = fmaf(yv.y, w1.z, acc.z); acc.w = fmaf(yv.y, w1.w, acc.w);
    float4 w2 = Wv[(k+2)*16 + l16];
    acc.x = fmaf(yv.z, w2.x, acc.x); acc.y = fmaf(yv.z, w2.y, acc.y);
    acc.z = fmaf(yv.z, w2.z, acc.z); acc.w = fmaf(yv.z, w2.w, acc.w);
    float4 w3 = Wv[(k+3)*16 + l16];
    acc.x = fmaf(yv.w, w3.x, acc.x); acc.y = fmaf(yv.w, w3.y, acc.y);
    acc.z = fmaf(yv.w, w3.z, acc.z); acc.w = fmaf(yv.w, w3.w, acc.w);
  }
  return acc;
}

// LayerNorm of 8 rows x 96 cols (256 threads: 8 groups of 32 lanes).
__device__ __forceinline__ void ln8(const float* __restrict__ in, int instride,
                                    float* __restrict__ out, int outstride,
                                    const float* __restrict__ g, const float* __restrict__ b,
                                    int t)
{
  const int r = t >> 5, l = t & 31;
  const float* row = in + r*instride;
  float a0 = row[l], a1 = row[l+32], a2 = row[l+64];
  float s1 = a0 + a1 + a2;
  float s2 = a0*a0 + a1*a1 + a2*a2;
  #pragma unroll
  for (int off = 16; off >= 1; off >>= 1){
    s1 += __shfl_xor(s1, off);
    s2 += __shfl_xor(s2, off);
  }
  float mean = s1 * (1.f/96.f);
  float var  = s2 * (1.f/96.f) - mean*mean;
  float rs = rsqrtf(var + 1e-5f);
  float* orow = out + r*outstride;
  orow[l]    = (a0-mean)*rs*g[l]    + b[l];
  orow[l+32] = (a1-mean)*rs*g[l+32] + b[l+32];
  orow[l+64] = (a2-mean)*rs*g[l+64] + b[l+64];
}

// LayerNorm of a single 96-row (threads 0..31).
__device__ __forceinline__ void lnrow(const float* __restrict__ in,
                                      float* __restrict__ out,
                                      const float* __restrict__ g, const float* __restrict__ b,
                                      int t)
{
  if (t < 32){
    float a0 = in[t], a1 = in[t+32], a2 = in[t+64];
    float s1 = a0 + a1 + a2;
    float s2 = a0*a0 + a1*a1 + a2*a2;
    #pragma unroll
    for (int off = 16; off >= 1; off >>= 1){
      s1 += __shfl_xor(s1, off);
      s2 += __shfl_xor(s2, off);
    }
    float mean = s1 * (1.f/96.f);
    float var  = s2 * (1.f/96.f) - mean*mean;
    float rs = rsqrtf(var + 1e-5f);
    out[t]    = (a0-mean)*rs*g[t]    + b[t];
    out[t+32] = (a1-mean)*rs*g[t+32] + b[t+32];
    out[t+64] = (a2-mean)*rs*g[t+64] + b[t+64];
  }
}

// 8-row matmul: out[n][c] = act( sum_k in[n][k]*W[k][c] + b[c] ) (+ resid[n][c])
// thread -> (n = gi&7, c4 = gi>>3), float4 over columns.
template<int K, int COLS, bool GACT>
__device__ __forceinline__ void mm8(const float* __restrict__ in, int instride,
                                    const float* __restrict__ Wg, const float* __restrict__ bg,
                                    float* __restrict__ out, int outstride,
                                    const float* __restrict__ resid, int resstride, int t)
{
  static_assert(COLS % 4 == 0, "");
  const float4* W4  = (const float4*)Wg;
  const float4* b4p = (const float4*)bg;
  constexpr int NG = 8*(COLS/4);
  for (int gi = t; gi < NG; gi += 256){
    const int n  = gi & 7;
    const int c4 = gi >> 3;
    const float* inr = in + n*instride;
    float4 acc = bg ? b4p[c4] : make_float4(0.f,0.f,0.f,0.f);
    #pragma unroll 4
    for (int k = 0; k < K; ++k){
      const float xv = inr[k];
      const float4 w = W4[k*(COLS/4) + c4];
      acc.x = fmaf(xv, w.x, acc.x); acc.y = fmaf(xv, w.y, acc.y);
      acc.z = fmaf(xv, w.z, acc.z); acc.w = fmaf(xv, w.w, acc.w);
    }
    if (GACT){ acc.x = gelu_f(acc.x); acc.y = gelu_f(acc.y); acc.z = gelu_f(acc.z); acc.w = gelu_f(acc.w); }
    if (resid){
      const float* rr = resid + n*resstride + 4*c4;
      acc.x += rr[0]; acc.y += rr[1]; acc.z += rr[2]; acc.w += rr[3];
    }
    *(float4*)(out + n*outstride + 4*c4) = acc;
  }
}

// Single-row matvec: out[c] = act( sum_k in[k]*W[k][c] + b[c] ) (+ resid[c])
template<int K, int COLS, bool GACT>
__device__ __forceinline__ void mv1(const float* __restrict__ in,
                                    const float* __restrict__ Wg, const float* __restrict__ bg,
                                    float* __restrict__ out,
                                    const float* __restrict__ resid, int t)
{
  static_assert(COLS % 4 == 0, "");
  const float4* W4  = (const float4*)Wg;
  const float4* b4p = (const float4*)bg;
  if (t < COLS/4){
    float4 acc = bg ? b4p[t] : make_float4(0.f,0.f,0.f,0.f);
    #pragma unroll 4
    for (int k = 0; k < K; ++k){
      const float xv = in[k];
      const float4 w = W4[k*(COLS/4) + t];
      acc.x = fmaf(xv, w.x, acc.x); acc.y = fmaf(xv, w.y, acc.y);
      acc.z = fmaf(xv, w.z, acc.z); acc.w = fmaf(xv, w.w, acc.w);
    }
    if (GACT){ acc.x = gelu_f(acc.x); acc.y = gelu_f(acc.y); acc.z = gelu_f(acc.z); acc.w = gelu_f(acc.w); }
    if (resid){
      acc.x += resid[4*t+0]; acc.y += resid[4*t+1]; acc.z += resid[4*t+2]; acc.w += resid[4*t+3];
    }
    *(float4*)(out + 4*t) = acc;
  }
}

__global__ __launch_bounds__(256)
void MultiViewAggregation_41300405518369_kernel(Params P)
{
  __shared__ __align__(16) float smem[SM_TOT];
  const int t = threadIdx.x;
  const int p = blockIdx.x;

  // ======================= Phase A: PBR MLP =======================
  // Stage w1/w2/w3 into LDS (float4 copies).
  {
    float4* d1 = (float4*)(smem + A_W1); const float4* s1 = (const float4*)P.pbr_w1;
    for (int i = t; i < 112;  i += 256) d1[i] = s1[i];
    float4* d2 = (float4*)(smem + A_W2); const float4* s2 = (const float4*)P.pbr_w2;
    for (int i = t; i < 1024; i += 256) d2[i] = s2[i];
    float4* d3 = (float4*)(smem + A_W3); const float4* s3 = (const float4*)P.pbr_w3;
    for (int i = t; i < 1024; i += 256) d3[i] = s3[i];
  }
  __syncthreads();

  const int lane = t & 63;
  const int wv   = t >> 6;      // wave 0..3
  const int l16  = lane & 15;   // lane within group
  const int grp  = lane >> 4;   // group 0..3

  float gl[7], bl[7];
  #pragma unroll
  for (int k = 0; k < 7; ++k){ gl[k] = P.pbr_ln_g[k]; bl[k] = P.pbr_ln_b[k]; }
  const float nm0 = P.normal[p*3+0], nm1 = P.normal[p*3+1], nm2 = P.normal[p*3+2];
  const float b4a = P.pbr_b4[2*l16], b4b = P.pbr_b4[2*l16+1];

  float* yrow = smem + A_Y + (wv*4 + grp)*68;   // padded stride: conflict-free per group
  float fa = 0.f, fb = 0.f;                     // feature accumulator (cols 2*l16, 2*l16+1)

  for (int pass = 0; pass < 6; ++pass){
    const int nview = (pass >= 3 ? 4 : 0) + wv;
    const int j     = (pass % 3)*4 + grp;

    const float* vd = P.view_dir + (p*NV + nview)*3;
    const float vd0 = vd[0], vd1 = vd[1], vd2 = vd[2];
    const float* dl = P.DL + p*(SGN*7) + j*7;
    const float d0=dl[0], d1=dl[1], d2=dl[2], d3=dl[3], d4=dl[4], d5=dl[5], d6=dl[6];

    const float DLdotN = d0*nm0 + d1*nm1 + d2*nm2;
    const float hv     = (d0*vd0 + d1*vd1 + d2*vd2 + 1.f)*0.5f;
    const float fres   = exp2f((-5.55472f*hv - 6.98316f)*hv);
    const float VdotN  = vd0*nm0 + vd1*nm1 + vd2*nm2;

    float x[7] = {DLdotN, d3, d4, d5, d6, fres, VdotN};
    float m = (x[0]+x[1]+x[2]+x[3]+x[4]+x[5]+x[6])*(1.f/7.f);
    float var = 0.f;
    #pragma unroll
    for (int k = 0; k < 7; ++k){ float q = x[k]-m; var += q*q; }
    var *= (1.f/7.f);
    const float rs = rsqrtf(var + 1e-5f);
    float xl[7];
    #pragma unroll
    for (int k = 0; k < 7; ++k) xl[k] = (x[k]-m)*rs*gl[k] + bl[k];

    // layer1: 7 -> 64 (elu), lane computes cols 4*l16..+3
    {
      const float4* W1v = (const float4*)(smem + A_W1);
      float4 acc = ((const float4*)P.pbr_b1)[l16];
      #pragma unroll
      for (int k = 0; k < 7; ++k){
        float4 w = W1v[k*16 + l16];
        acc.x = fmaf(xl[k], w.x, acc.x); acc.y = fmaf(xl[k], w.y, acc.y);
        acc.z = fmaf(xl[k], w.z, acc.z); acc.w = fmaf(xl[k], w.w, acc.w);
      }
      float4 e; e.x = elu_f(acc.x); e.y = elu_f(acc.y); e.z = elu_f(acc.z); e.w = elu_f(acc.w);
      *(float4*)(yrow + 4*l16) = e;   // same-wave DS ops are in-order: no barrier needed
    }
    // layer2: 64 -> 64 (elu)
    {
      float4 acc = hidden64(yrow, smem + A_W2, P.pbr_b2, l16);
      float4 e; e.x = elu_f(acc.x); e.y = elu_f(acc.y); e.z = elu_f(acc.z); e.w = elu_f(acc.w);
      *(float4*)(yrow + 4*l16) = e;
    }
    // layer3: 64 -> 64 (elu)
    {
      float4 acc = hidden64(yrow, smem + A_W3, P.pbr_b3, l16);
      float4 e; e.x = elu_f(acc.x); e.y = elu_f(acc.y); e.z = elu_f(acc.z); e.w = elu_f(acc.w);
      *(float4*)(yrow + 4*l16) = e;
    }
    // layer4: 64 -> 32 (+b4 per sg), accumulate over sg; lane cols 2*l16, 2*l16+1
    {
      fa += b4a; fb += b4b;
      const float2* W4v = (const float2*)P.pbr_w4;
      #pragma unroll 8
      for (int k = 0; k < 64; k += 4){
        float4 yv = *(const float4*)(yrow + k);
        float2 wA = W4v[(k+0)*16 + l16]; fa = fmaf(yv.x, wA.x, fa); fb = fmaf(yv.x, wA.y, fb);
        float2 wB = W4v[(k+1)*16 + l16]; fa = fmaf(yv.y, wB.x, fa); fb = fmaf(yv.y, wB.y, fb);
        float2 wC = W4v[(k+2)*16 + l16]; fa = fmaf(yv.z, wC.x, fa); fb = fmaf(yv.z, wC.y, fb);
        float2 wD = W4v[(k+3)*16 + l16]; fa = fmaf(yv.w, wD.x, fa); fb = fmaf(yv.w, wD.y, fb);
      }
    }
    if ((pass % 3) == 2){
      // sum the 4 groups (4 sg each -> 12 sg total for this view)
      fa += __shfl_xor(fa, 16); fa += __shfl_xor(fa, 32);
      fb += __shfl_xor(fb, 16); fb += __shfl_xor(fb, 32);
      if (grp == 0){
        smem[SM_FEAT + nview*32 + 2*l16]     = fa;
        smem[SM_FEAT + nview*32 + 2*l16 + 1] = fb;
      }
      fa = 0.f; fb = 0.f;
    }
  }
  __syncthreads();

  // ======================= Phase B: per-pixel =======================
  // B0: view weights
  if (t < 8){
    float pe = P.proj_err[p*NV + t];
    float a  = log10f(fabsf(pe) + 1e-6f);
    smem[SM_WGT + t] = fmaxf(-a, 0.f);
  }
  __syncthreads();
  if (t == 0){
    float s = 0.f;
    for (int n = 0; n < 8; ++n) s += smem[SM_WGT + n];
    float inv = 1.f/(s + 1e-6f);
    for (int n = 0; n < 8; ++n) smem[SM_WGT + 8 + n] = smem[SM_WGT + n]*inv;
  }
  // B1: x_input = [rgb(3) | fm(61) | pbr_feature(32)]
  for (int idx = t; idx < 768; idx += 256){
    int n = idx / 96, k = idx - n*96;
    float val;
    if (k < 3)       val = P.rgb[(p*NV + n)*3 + k];
    else if (k < 64) val = P.fm[p*61 + (k-3)];
    else             val = smem[SM_FEAT + n*32 + (k-64)];
    smem[SM_XIN + idx] = val;
  }
  __syncthreads();

  // v = LN(xin) @ tv1_w
  ln8(smem + SM_XIN, 96, smem + B_XLN, 100, P.tv1_ln_g, P.tv1_ln_b, t);
  __syncthreads();
  mm8<96, 32, false>(smem + B_XLN, 100, P.tv1_w, nullptr, smem + SM_V, 32, nullptr, 0, t);
  __syncthreads();

  // weighted mean/var over views
  if (t < 32){
    const float* wn = smem + SM_WGT + 8;
    float mmv = 0.f;
    for (int n = 0; n < 8; ++n) mmv += wn[n]*smem[SM_V + n*32 + t];
    smem[SM_MEAN + t] = mmv;
    float vv = 0.f;
    for (int n = 0; n < 8; ++n){ float d = smem[SM_V + n*32 + t] - mmv; vv += wn[n]*d*d; }
    smem[SM_VAR + t] = vv;
  }
  __syncthreads();

  // xcat = [v | mean | var] per view -> B_XLN
  for (int idx = t; idx < 768; idx += 256){
    int n = idx / 96, k = idx - n*96;
    float val = (k < 32) ? smem[SM_V + n*32 + k]
              : (k < 64) ? smem[SM_MEAN + (k-32)]
                         : smem[SM_VAR + (k-64)];
    smem[B_XLN + n*100 + k] = val;
  }
  __syncthreads();
  // x = xcat @ to1_w + to1_b + xin
  mm8<96, 96, false>(smem + B_XLN, 100, P.to1_w, P.to1_b, smem + SM_XCUR, 96, smem + SM_XIN, 96, t);
  __syncthreads();

  // x = gelu(LN(x) @ n1_w1 + b1) @ n1_w2 + b2 + xin
  ln8(smem + SM_XCUR, 96, smem + B_XLN, 100, P.n1_ln_g, P.n1_ln_b, t);
  __syncthreads();
  mm8<96, 256, true>(smem + B_XLN, 100, P.n1_w1, P.n1_b1, smem + B_H, 260, nullptr, 0, t);
  __syncthreads();
  mm8<256, 96, false>(smem + B_H, 260, P.n1_w2, P.n1_b2, smem + SM_XCUR, 96, smem + SM_XIN, 96, t);
  __syncthreads();

  // v2 = LN(x) @ tv2_w ; weighted mean/var
  ln8(smem + SM_XCUR, 96, smem + B_XLN, 100, P.tv2_ln_g, P.tv2_ln_b, t);
  __syncthreads();
  mm8<96, 32, false>(smem + B_XLN, 100, P.tv2_w, nullptr, smem + SM_V, 32, nullptr, 0, t);
  __syncthreads();
  if (t < 32){
    const float* wn = smem + SM_WGT + 8;
    float mmv = 0.f;
    for (int n = 0; n < 8; ++n) mmv += wn[n]*smem[SM_V + n*32 + t];
    smem[SM_MEAN + t] = mmv;
    float vv = 0.f;
    for (int n = 0; n < 8; ++n){ float d = smem[SM_V + n*32 + t] - mmv; vv += wn[n]*d*d; }
    smem[SM_VAR + t] = vv;
  }
  __syncthreads();

  // xs = [v2[0] | mean | var] @ to2_w + to2_b + xin[0]
  if (t < 96){
    float val = (t < 32) ? smem[SM_V + t]
              : (t < 64) ? smem[SM_MEAN + (t-32)]
                         : smem[SM_VAR + (t-64)];
    smem[SM_XSLN + t] = val;   // reuse XSLN as the cat-row scratch
  }
  __syncthreads();
  mv1<96, 96, false>(smem + SM_XSLN, P.to2_w, P.to2_b, smem + SM_XS, smem + SM_XIN /*row 0*/, t);
  __syncthreads();

  // xs = gelu(LN(xs) @ n2_w1 + b1) @ n2_w2 + b2 + xin[0]
  lnrow(smem + SM_XS, smem + SM_XSLN, P.n2_ln_g, P.n2_ln_b, t);
  __syncthreads();
  mv1<96, 256, true>(smem + SM_XSLN, P.n2_w1, P.n2_b1, smem + B_H, nullptr, t);
  __syncthreads();
  mv1<256, 96, false>(smem + B_H, P.n2_w2, P.n2_b2, smem + SM_XS, smem + SM_XIN /*row 0*/, t);
  __syncthreads();

  // brdf = gelu(LN(xs) @ brdf_w1 + b1) @ brdf_w2 + b2  -> global out
  lnrow(smem + SM_XS, smem + SM_XSLN, P.brdf_ln_g, P.brdf_ln_b, t);
  __syncthreads();
  mv1<96, 128, true>(smem + SM_XSLN, P.brdf_w1, P.brdf_b1, smem + B_H, nullptr, t);
  __syncthreads();
  mv1<128, 128, false>(smem + B_H, P.brdf_w2, P.brdf_b2, P.out + (size_t)p*128, nullptr, t);
}

extern "C" void kernel_launch(void* const* d_in, const int* in_sizes, int n_in,
                              void* d_out, int out_size, void* d_ws, size_t ws_size,
                              hipStream_t stream)
{
  (void)in_sizes; (void)n_in; (void)d_ws; (void)ws_size; (void)out_size;
  Params P;
  int i = 0;
  P.rgb       = (const float*)d_in[i++];
  P.fm        = (const float*)d_in[i++];
  P.view_dir  = (const float*)d_in[i++];
  P.proj_err  = (const float*)d_in[i++];
  P.normal    = (const float*)d_in[i++];
  P.DL        = (const float*)d_in[i++];
  P.pbr_ln_g  = (const float*)d_in[i++];
  P.pbr_ln_b  = (const float*)d_in[i++];
  P.pbr_w1    = (const float*)d_in[i++];
  P.pbr_b1    = (const float*)d_in[i++];
  P.pbr_w2    = (const float*)d_in[i++];
  P.pbr_b2    = (const float*)d_in[i++];
  P.pbr_w3    = (const float*)d_in[i++];
  P.pbr_b3    = (const float*)d_in[i++];
  P.pbr_w4    = (const float*)d_in[i++];
  P.pbr_b4    = (const float*)d_in[i++];
  P.tv1_ln_g  = (const float*)d_in[i++];
  P.tv1_ln_b  = (const float*)d_in[i++];
  P.tv1_w     = (const float*)d_in[i++];
  P.to1_w     = (const float*)d_in[i++];
  P.to1_b     = (const float*)d_in[i++];
  P.n1_ln_g   = (const float*)d_in[i++];
  P.n1_ln_b   = (const float*)d_in[i++];
  P.n1_w1     = (const float*)d_in[i++];
  P.n1_b1     = (const float*)d_in[i++];
  P.n1_w2     = (const float*)d_in[i++];
  P.n1_b2     = (const float*)d_in[i++];
  P.tv2_ln_g  = (const float*)d_in[i++];
  P.tv2_ln_b  = (const float*)d_in[i++];
  P.tv2_w     = (const float*)d_in[i++];
  P.to2_w     = (const float*)d_in[i++];
  P.to2_b     = (const float*)d_in[i++];
  P.n2_ln_g   = (const float*)d_in[i++];
  P.n2_ln_b   = (const float*)d_in[i++];
  P.n2_w1     = (const float*)d_in[i++];
  P.n2_b1     = (const float*)d_in[i++];
  P.n2_w2     = (const float*)d_in[i++];
  P.n2_b2     = (const float*)d_in[i++];
  P.brdf_ln_g = (const float*)d_in[i++];
  P.brdf_ln_b = (const float*)d_in[i++];
  P.brdf_w1   = (const float*)d_in[i++];
  P.brdf_b1   = (const float*)d_in[i++];
  P.brdf_w2   = (const float*)d_in[i++];
  P.brdf_b2   = (const float*)d_in[i++];
  P.out       = (float*)d_out;

  MultiViewAggregation_41300405518369_kernel<<<dim3(NPIX), dim3(256), 0, stream>>>(P);
}

// Round 2
// 1548.665 us; speedup vs baseline: 1.5122x; 1.5122x over previous
//
#include <hip/hip_runtime.h>
#include <math.h>

// MultiViewAggregation — fp32, instance-per-thread Phase A + 32-row batched Phase B.
// Block = 384 threads (6 waves) processes PPB=4 pixels.
// Phase A: 384 instances (4px x 8view x 12sg), one per thread; y[64] in VGPRs,
//          weights broadcast-read from LDS (uniform addr -> no conflicts).
// Phase B: rows = 32 (4px x 8views); unit=(col4,rowpair) matmuls, weights from L2.

#define NPIX 16384
#define PPB 4
#define NBLK (NPIX / PPB)
#define NTHR 384

struct Params {
  const float* rgb; const float* fm; const float* view_dir; const float* proj_err;
  const float* normal; const float* DL;
  const float* pbr_ln_g; const float* pbr_ln_b;
  const float* pbr_w1; const float* pbr_b1; const float* pbr_w2; const float* pbr_b2;
  const float* pbr_w3; const float* pbr_b3; const float* pbr_w4; const float* pbr_b4;
  const float* tv1_ln_g; const float* tv1_ln_b; const float* tv1_w;
  const float* to1_w; const float* to1_b;
  const float* n1_ln_g; const float* n1_ln_b; const float* n1_w1; const float* n1_b1;
  const float* n1_w2; const float* n1_b2;
  const float* tv2_ln_g; const float* tv2_ln_b; const float* tv2_w;
  const float* to2_w; const float* to2_b;
  const float* n2_ln_g; const float* n2_ln_b; const float* n2_w1; const float* n2_b1;
  const float* n2_w2; const float* n2_b2;
  const float* brdf_ln_g; const float* brdf_ln_b; const float* brdf_w1; const float* brdf_b1;
  const float* brdf_w2; const float* brdf_b2;
  float* out;
};

// ---------------- LDS layout (float offsets) ----------------
// UNION region (Phase A weights | featbuf | Phase B scratch):
constexpr int AW1 = 0;        // 7*64
constexpr int AW2 = 448;      // 64*64
constexpr int AW3 = 4544;     // 64*64
constexpr int AW4 = 8640;     // 64*32
constexpr int AB1 = 10688;    // 64
constexpr int AB2 = 10752;
constexpr int AB3 = 10816;
constexpr int AB4 = 10880;    // 32
constexpr int ALG = 10912;    // 7
constexpr int ALB = 10919;    // 7  -> A end 10926
constexpr int FB  = 0;        // featbuf [6][32][36] = 6912 (after A weights dead)
constexpr int XLN = 0;        // [32][98] = 3136
constexpr int HID = 3136;     // [32][258] = 8256 -> union end 11392
constexpr int UEND = 11392;
// Persistent:
constexpr int XIN   = UEND;          // [32][96] = 3072
constexpr int XCUR  = XIN + 3072;    // [32][96] = 3072
constexpr int VB    = XCUR + 3072;   // [32][32] = 1024
constexpr int MEANB = VB + 1024;     // [4][32]
constexpr int VARB  = MEANB + 128;   // [4][32]
constexpr int WGTB  = VARB + 128;    // 32 (normalized)
constexpr int XSB   = WGTB + 32;     // [4][96]
constexpr int XSLNB = XSB + 384;     // [4][96]
constexpr int SMTOT = XSLNB + 384;   // 19616 floats = 76.6 KB -> 2 blocks/CU

__device__ __forceinline__ float elu_f(float x){ return x > 0.f ? x : (__expf(x) - 1.f); }
__device__ __forceinline__ float gelu_f(float x){ return 0.5f*x*(1.f + erff(x*0.70710678118654752f)); }
__device__ __forceinline__ void fma4(float4& a, float s, const float4 w){
  a.x = fmaf(s, w.x, a.x); a.y = fmaf(s, w.y, a.y);
  a.z = fmaf(s, w.z, a.z); a.w = fmaf(s, w.w, a.w);
}

// LayerNorm over 32 rows x 96 cols. 8-lane groups (t<256). Bank-staggered cols.
__device__ __forceinline__ void ln32(const float* __restrict__ in, int S,
                                     float* __restrict__ out, int So,
                                     const float* __restrict__ g, const float* __restrict__ b,
                                     int t)
{
  if (t < 256){
    const int r = t >> 3, l8 = t & 7;
    const float* row = in + r*S;
    float vals[12]; int cols[12];
    float s1 = 0.f, s2 = 0.f;
    #pragma unroll
    for (int i = 0; i < 12; ++i){
      int c = l8 + 8*i + 8*(r & 7); if (c >= 96) c -= 96;   // stagger: conflict-free
      float a = row[c];
      cols[i] = c; vals[i] = a;
      s1 += a; s2 += a*a;
    }
    s1 += __shfl_xor(s1, 1); s2 += __shfl_xor(s2, 1);
    s1 += __shfl_xor(s1, 2); s2 += __shfl_xor(s2, 2);
    s1 += __shfl_xor(s1, 4); s2 += __shfl_xor(s2, 4);
    float mean = s1*(1.f/96.f);
    float var  = s2*(1.f/96.f) - mean*mean;
    float rs = rsqrtf(var + 1e-5f);
    float* orow = out + r*So;
    #pragma unroll
    for (int i = 0; i < 12; ++i){
      int c = cols[i];
      orow[c] = (vals[i]-mean)*rs*g[c] + b[c];
    }
  }
}

// LayerNorm of 4 rows x 96 (t<32).
__device__ __forceinline__ void ln4(const float* __restrict__ in, int S,
                                    float* __restrict__ out, int So,
                                    const float* __restrict__ g, const float* __restrict__ b,
                                    int t)
{
  if (t < 32){
    const int r = t >> 3, l8 = t & 7;
    const float* row = in + r*S;
    float vals[12];
    float s1 = 0.f, s2 = 0.f;
    #pragma unroll
    for (int i = 0; i < 12; ++i){
      float a = row[l8 + 8*i];
      vals[i] = a; s1 += a; s2 += a*a;
    }
    s1 += __shfl_xor(s1, 1); s2 += __shfl_xor(s2, 1);
    s1 += __shfl_xor(s1, 2); s2 += __shfl_xor(s2, 2);
    s1 += __shfl_xor(s1, 4); s2 += __shfl_xor(s2, 4);
    float mean = s1*(1.f/96.f);
    float var  = s2*(1.f/96.f) - mean*mean;
    float rs = rsqrtf(var + 1e-5f);
    float* orow = out + r*So;
    #pragma unroll
    for (int i = 0; i < 12; ++i){
      int c = l8 + 8*i;
      orow[c] = (vals[i]-mean)*rs*g[c] + b[c];
    }
  }
}

// 32-row matmul: out[r][c] = act(sum_k in[r][k]*W[k][c] + b) (+resid).
// unit = (c4, rowpair): 16 lanes share a weight float4 (broadcast transaction).
template<int K, int C, bool GELU, bool HASB, bool RES>
__device__ __forceinline__ void mm32(const float* __restrict__ inb, int S,
                                     const float* __restrict__ Wg, const float* __restrict__ bg,
                                     float* __restrict__ outb, int So,
                                     const float* __restrict__ residb, int Sr, int t)
{
  constexpr int C4 = C/4;
  const float4* __restrict__ W4 = (const float4*)Wg;
  for (int gi = t; gi < C4*16; gi += NTHR){
    const int rp = gi & 15, c4 = gi >> 4;
    const float2* x0 = (const float2*)(inb + (2*rp)*S);
    const float2* x1 = (const float2*)(inb + (2*rp+1)*S);
    float4 a0 = HASB ? ((const float4*)bg)[c4] : make_float4(0.f,0.f,0.f,0.f);
    float4 a1 = a0;
    #pragma unroll 4
    for (int k2 = 0; k2 < K/2; ++k2){
      float2 xa = x0[k2], xb = x1[k2];
      float4 wA = W4[(2*k2)*C4 + c4];
      float4 wB = W4[(2*k2+1)*C4 + c4];
      fma4(a0, xa.x, wA); fma4(a0, xa.y, wB);
      fma4(a1, xb.x, wA); fma4(a1, xb.y, wB);
    }
    if (GELU){
      a0.x=gelu_f(a0.x); a0.y=gelu_f(a0.y); a0.z=gelu_f(a0.z); a0.w=gelu_f(a0.w);
      a1.x=gelu_f(a1.x); a1.y=gelu_f(a1.y); a1.z=gelu_f(a1.z); a1.w=gelu_f(a1.w);
    }
    if (RES){
      const float* r0 = residb + (2*rp)*Sr + 4*c4;
      const float* r1 = residb + (2*rp+1)*Sr + 4*c4;
      a0.x += r0[0]; a0.y += r0[1]; a0.z += r0[2]; a0.w += r0[3];
      a1.x += r1[0]; a1.y += r1[1]; a1.z += r1[2]; a1.w += r1[3];
    }
    float* o0 = outb + (2*rp)*So + 4*c4;
    float* o1 = outb + (2*rp+1)*So + 4*c4;
    o0[0]=a0.x; o0[1]=a0.y; o0[2]=a0.z; o0[3]=a0.w;
    o1[0]=a1.x; o1[1]=a1.y; o1[2]=a1.z; o1[3]=a1.w;
  }
}

// 4-row (per-pixel) matmul with k-split-2: unit=(c, khalf); combine via shfl_xor(1).
template<int K, int C, bool GELU, bool HASB, bool RES>
__device__ __forceinline__ void mmpx(const float* __restrict__ inb, int S,
                                     const float* __restrict__ Wg, const float* __restrict__ bg,
                                     float* __restrict__ outb, int So,
                                     const float* __restrict__ residb, int Sr, int t)
{
  for (int gi = t; gi < 2*C; gi += NTHR){
    const int kh = gi & 1, c = gi >> 1;
    float4 a = make_float4(0.f,0.f,0.f,0.f);
    const int k0 = kh*(K/2);
    #pragma unroll 4
    for (int kk = 0; kk < K/2; ++kk){
      const int k = k0 + kk;
      float w = Wg[k*C + c];
      a.x = fmaf(inb[0*S + k], w, a.x);
      a.y = fmaf(inb[1*S + k], w, a.y);
      a.z = fmaf(inb[2*S + k], w, a.z);
      a.w = fmaf(inb[3*S + k], w, a.w);
    }
    a.x += __shfl_xor(a.x, 1); a.y += __shfl_xor(a.y, 1);
    a.z += __shfl_xor(a.z, 1); a.w += __shfl_xor(a.w, 1);
    if (kh == 0){
      if (HASB){ float b = bg[c]; a.x+=b; a.y+=b; a.z+=b; a.w+=b; }
      if (GELU){ a.x=gelu_f(a.x); a.y=gelu_f(a.y); a.z=gelu_f(a.z); a.w=gelu_f(a.w); }
      if (RES){
        a.x += residb[0*Sr + c]; a.y += residb[1*Sr + c];
        a.z += residb[2*Sr + c]; a.w += residb[3*Sr + c];
      }
      outb[0*So + c] = a.x; outb[1*So + c] = a.y;
      outb[2*So + c] = a.z; outb[3*So + c] = a.w;
    }
  }
}

__global__ __launch_bounds__(NTHR, 3)
void MultiViewAggregation_41300405518369_kernel(Params P)
{
  __shared__ __align__(16) float smem[SMTOT];
  const int t = threadIdx.x;
  const int bpx0 = blockIdx.x * PPB;

  // ---- stage Phase A weights into LDS ----
  {
    const float4* s; float4* d;
    s = (const float4*)P.pbr_w1; d = (float4*)(smem+AW1);
    for (int i = t; i < 112;  i += NTHR) d[i] = s[i];
    s = (const float4*)P.pbr_w2; d = (float4*)(smem+AW2);
    for (int i = t; i < 1024; i += NTHR) d[i] = s[i];
    s = (const float4*)P.pbr_w3; d = (float4*)(smem+AW3);
    for (int i = t; i < 1024; i += NTHR) d[i] = s[i];
    s = (const float4*)P.pbr_w4; d = (float4*)(smem+AW4);
    for (int i = t; i < 512;  i += NTHR) d[i] = s[i];
    if (t < 16)      ((float4*)(smem+AB1))[t] = ((const float4*)P.pbr_b1)[t];
    else if (t < 32) ((float4*)(smem+AB2))[t-16] = ((const float4*)P.pbr_b2)[t-16];
    else if (t < 48) ((float4*)(smem+AB3))[t-32] = ((const float4*)P.pbr_b3)[t-32];
    else if (t < 56) ((float4*)(smem+AB4))[t-48] = ((const float4*)P.pbr_b4)[t-48];
    else if (t < 63) smem[ALG + t-56] = P.pbr_ln_g[t-56];
    else if (t < 70) smem[ALB + t-63] = P.pbr_ln_b[t-63];
  }
  __syncthreads();

  // ================= Phase A: one (px,view,sg) instance per thread =================
  const int pair = t & 31;        // (px_l, view)
  const int sg   = t >> 5;        // 0..11
  const int px_l = pair >> 3;
  const int view = pair & 7;
  const int px   = bpx0 + px_l;
  const int lane = t & 63;
  const int wv   = t >> 6;

  float f[32];
  {
    const float* nrm = P.normal + px*3;
    const float nm0 = nrm[0], nm1 = nrm[1], nm2 = nrm[2];
    const float* vd = P.view_dir + (px*8 + view)*3;
    const float vd0 = vd[0], vd1 = vd[1], vd2 = vd[2];
    const float* dl = P.DL + px*84 + sg*7;
    const float d0=dl[0], d1=dl[1], d2=dl[2], d3=dl[3], d4=dl[4], d5=dl[5], d6=dl[6];

    const float DLdotN = d0*nm0 + d1*nm1 + d2*nm2;
    const float hv     = (d0*vd0 + d1*vd1 + d2*vd2 + 1.f)*0.5f;
    const float fres   = exp2f((-5.55472f*hv - 6.98316f)*hv);
    const float VdotN  = vd0*nm0 + vd1*nm1 + vd2*nm2;

    float x[7] = {DLdotN, d3, d4, d5, d6, fres, VdotN};
    float m = (x[0]+x[1]+x[2]+x[3]+x[4]+x[5]+x[6])*(1.f/7.f);
    float var = 0.f;
    #pragma unroll
    for (int k = 0; k < 7; ++k){ float q = x[k]-m; var += q*q; }
    var *= (1.f/7.f);
    const float rs = rsqrtf(var + 1e-5f);
    float xl[7];
    #pragma unroll
    for (int k = 0; k < 7; ++k) xl[k] = (x[k]-m)*rs*smem[ALG+k] + smem[ALB+k];

    // layer1: 7 -> 64 (elu). Uniform LDS broadcast reads.
    float y[64];
    {
      const float4* W1 = (const float4*)(smem + AW1);
      #pragma unroll
      for (int c4 = 0; c4 < 16; ++c4){
        float4 acc = *(const float4*)(smem + AB1 + 4*c4);
        #pragma unroll
        for (int k = 0; k < 7; ++k) fma4(acc, xl[k], W1[k*16 + c4]);
        y[4*c4+0] = elu_f(acc.x); y[4*c4+1] = elu_f(acc.y);
        y[4*c4+2] = elu_f(acc.z); y[4*c4+3] = elu_f(acc.w);
      }
    }
    // layers 2,3: 64 -> 64 (elu). One code body, runtime L.
    for (int L = 0; L < 2; ++L){
      const float4* W = (const float4*)(smem + (L ? AW3 : AW2));
      const float*  B = smem + (L ? AB3 : AB2);
      float yn[64];
      #pragma unroll
      for (int c8 = 0; c8 < 8; ++c8){
        float4 aA = *(const float4*)(B + 8*c8);
        float4 aB = *(const float4*)(B + 8*c8 + 4);
        #pragma unroll
        for (int k = 0; k < 64; ++k){
          const float yv = y[k];
          fma4(aA, yv, W[k*16 + 2*c8]);
          fma4(aB, yv, W[k*16 + 2*c8 + 1]);
        }
        yn[8*c8+0]=elu_f(aA.x); yn[8*c8+1]=elu_f(aA.y); yn[8*c8+2]=elu_f(aA.z); yn[8*c8+3]=elu_f(aA.w);
        yn[8*c8+4]=elu_f(aB.x); yn[8*c8+5]=elu_f(aB.y); yn[8*c8+6]=elu_f(aB.z); yn[8*c8+7]=elu_f(aB.w);
      }
      #pragma unroll
      for (int i = 0; i < 64; ++i) y[i] = yn[i];
    }
    // layer4: 64 -> 32 (+b4), no act.
    {
      const float4* W = (const float4*)(smem + AW4);
      #pragma unroll
      for (int c4 = 0; c4 < 8; ++c4){
        float4 acc = *(const float4*)(smem + AB4 + 4*c4);
        #pragma unroll
        for (int k = 0; k < 64; ++k) fma4(acc, y[k], W[k*8 + c4]);
        f[4*c4+0]=acc.x; f[4*c4+1]=acc.y; f[4*c4+2]=acc.z; f[4*c4+3]=acc.w;
      }
    }
  }
  // sg-reduction: pair lives at lane and lane+32 (sg 2w, 2w+1)
  #pragma unroll
  for (int i = 0; i < 32; ++i) f[i] += __shfl_xor(f[i], 32);

  __syncthreads();   // A weights dead; featbuf may alias
  if (lane < 32){
    float* fb = smem + FB + wv*1152 + pair*36;
    #pragma unroll
    for (int i = 0; i < 8; ++i)
      *(float4*)(fb + 4*i) = make_float4(f[4*i], f[4*i+1], f[4*i+2], f[4*i+3]);
  }
  __syncthreads();

  // reduce 6 waves -> xin[:,64..95]; fill rgb/fm; view weights
  for (int u = t; u < 1024; u += NTHR){
    const int pr = u & 31, c = u >> 5;
    float s = 0.f;
    #pragma unroll
    for (int w = 0; w < 6; ++w) s += smem[FB + w*1152 + pr*36 + c];
    smem[XIN + pr*96 + 64 + c] = s;
  }
  for (int idx = t; idx < 2048; idx += NTHR){
    const int r = idx >> 6, k = idx & 63;
    const int pl = r >> 3, v8 = r & 7;
    float val = (k < 3) ? P.rgb[((bpx0+pl)*8 + v8)*3 + k]
                        : P.fm[(bpx0+pl)*61 + (k-3)];
    smem[XIN + r*96 + k] = val;
  }
  if (t < 32){
    float pe = P.proj_err[(bpx0 + (t>>3))*8 + (t&7)];
    float wraw = fmaxf(-log10f(fabsf(pe) + 1e-6f), 0.f);
    float s = wraw;
    s += __shfl_xor(s, 1); s += __shfl_xor(s, 2); s += __shfl_xor(s, 4);
    smem[WGTB + t] = wraw / (s + 1e-6f);
  }
  __syncthreads();

  // ================= Phase B =================
  // v = LN(xin) @ tv1_w
  ln32(smem+XIN, 96, smem+XLN, 98, P.tv1_ln_g, P.tv1_ln_b, t);
  __syncthreads();
  mm32<96,32,false,false,false>(smem+XLN, 98, P.tv1_w, nullptr, smem+VB, 32, nullptr, 0, t);
  __syncthreads();
  if (t < 128){
    const int pl = t >> 5, c = t & 31;
    const float* wn = smem + WGTB + pl*8;
    float m = 0.f;
    #pragma unroll
    for (int v = 0; v < 8; ++v) m += wn[v]*smem[VB + (pl*8+v)*32 + c];
    float vv = 0.f;
    #pragma unroll
    for (int v = 0; v < 8; ++v){ float d = smem[VB + (pl*8+v)*32 + c] - m; vv += wn[v]*d*d; }
    smem[MEANB + pl*32 + c] = m;
    smem[VARB  + pl*32 + c] = vv;
  }
  __syncthreads();
  // xcat = [v | mean | var] -> XLN
  for (int u = t; u < 3072; u += NTHR){
    const int r = u & 31, k = u >> 5;
    const int pl = r >> 3;
    float val = (k < 32) ? smem[VB + r*32 + k]
              : (k < 64) ? smem[MEANB + pl*32 + (k-32)]
                         : smem[VARB + pl*32 + (k-64)];
    smem[XLN + r*98 + k] = val;
  }
  __syncthreads();
  mm32<96,96,false,true,true>(smem+XLN, 98, P.to1_w, P.to1_b, smem+XCUR, 96, smem+XIN, 96, t);
  __syncthreads();

  // n1 block
  ln32(smem+XCUR, 96, smem+XLN, 98, P.n1_ln_g, P.n1_ln_b, t);
  __syncthreads();
  mm32<96,256,true,true,false>(smem+XLN, 98, P.n1_w1, P.n1_b1, smem+HID, 258, nullptr, 0, t);
  __syncthreads();
  mm32<256,96,false,true,true>(smem+HID, 258, P.n1_w2, P.n1_b2, smem+XCUR, 96, smem+XIN, 96, t);
  __syncthreads();

  // tv2 + weighted stats
  ln32(smem+XCUR, 96, smem+XLN, 98, P.tv2_ln_g, P.tv2_ln_b, t);
  __syncthreads();
  mm32<96,32,false,false,false>(smem+XLN, 98, P.tv2_w, nullptr, smem+VB, 32, nullptr, 0, t);
  __syncthreads();
  if (t < 128){
    const int pl = t >> 5, c = t & 31;
    const float* wn = smem + WGTB + pl*8;
    float m = 0.f;
    #pragma unroll
    for (int v = 0; v < 8; ++v) m += wn[v]*smem[VB + (pl*8+v)*32 + c];
    float vv = 0.f;
    #pragma unroll
    for (int v = 0; v < 8; ++v){ float d = smem[VB + (pl*8+v)*32 + c] - m; vv += wn[v]*d*d; }
    smem[MEANB + pl*32 + c] = m;
    smem[VARB  + pl*32 + c] = vv;
  }
  __syncthreads();
  // xcat2 per pixel: [v[row0] | mean | var] -> XLN rows 0..3
  if (t < 384){
    const int pl = t / 96, k = t - pl*96;
    float val = (k < 32) ? smem[VB + (pl*8)*32 + k]
              : (k < 64) ? smem[MEANB + pl*32 + (k-32)]
                         : smem[VARB + pl*32 + (k-64)];
    smem[XLN + pl*98 + k] = val;
  }
  __syncthreads();
  // to2 (+xin row0 resid)
  mmpx<96,96,false,true,true>(smem+XLN, 98, P.to2_w, P.to2_b, smem+XSB, 96, smem+XIN, 768, t);
  __syncthreads();

  // n2 block (per pixel)
  ln4(smem+XSB, 96, smem+XSLNB, 96, P.n2_ln_g, P.n2_ln_b, t);
  __syncthreads();
  mmpx<96,256,true,true,false>(smem+XSLNB, 96, P.n2_w1, P.n2_b1, smem+HID, 258, nullptr, 0, t);
  __syncthreads();
  mmpx<256,96,false,true,true>(smem+HID, 258, P.n2_w2, P.n2_b2, smem+XSB, 96, smem+XIN, 768, t);
  __syncthreads();

  // brdf head
  ln4(smem+XSB, 96, smem+XSLNB, 96, P.brdf_ln_g, P.brdf_ln_b, t);
  __syncthreads();
  mmpx<96,128,true,true,false>(smem+XSLNB, 96, P.brdf_w1, P.brdf_b1, smem+HID, 258, nullptr, 0, t);
  __syncthreads();
  mmpx<128,128,false,true,false>(smem+HID, 258, P.brdf_w2, P.brdf_b2,
                                 P.out + (size_t)bpx0*128, 128, nullptr, 0, t);
}

extern "C" void kernel_launch(void* const* d_in, const int* in_sizes, int n_in,
                              void* d_out, int out_size, void* d_ws, size_t ws_size,
                              hipStream_t stream)
{
  (void)in_sizes; (void)n_in; (void)d_ws; (void)ws_size; (void)out_size;
  Params P;
  int i = 0;
  P.rgb       = (const float*)d_in[i++];
  P.fm        = (const float*)d_in[i++];
  P.view_dir  = (const float*)d_in[i++];
  P.proj_err  = (const float*)d_in[i++];
  P.normal    = (const float*)d_in[i++];
  P.DL        = (const float*)d_in[i++];
  P.pbr_ln_g  = (const float*)d_in[i++];
  P.pbr_ln_b  = (const float*)d_in[i++];
  P.pbr_w1    = (const float*)d_in[i++];
  P.pbr_b1    = (const float*)d_in[i++];
  P.pbr_w2    = (const float*)d_in[i++];
  P.pbr_b2    = (const float*)d_in[i++];
  P.pbr_w3    = (const float*)d_in[i++];
  P.pbr_b3    = (const float*)d_in[i++];
  P.pbr_w4    = (const float*)d_in[i++];
  P.pbr_b4    = (const float*)d_in[i++];
  P.tv1_ln_g  = (const float*)d_in[i++];
  P.tv1_ln_b  = (const float*)d_in[i++];
  P.tv1_w     = (const float*)d_in[i++];
  P.to1_w     = (const float*)d_in[i++];
  P.to1_b     = (const float*)d_in[i++];
  P.n1_ln_g   = (const float*)d_in[i++];
  P.n1_ln_b   = (const float*)d_in[i++];
  P.n1_w1     = (const float*)d_in[i++];
  P.n1_b1     = (const float*)d_in[i++];
  P.n1_w2     = (const float*)d_in[i++];
  P.n1_b2     = (const float*)d_in[i++];
  P.tv2_ln_g  = (const float*)d_in[i++];
  P.tv2_ln_b  = (const float*)d_in[i++];
  P.tv2_w     = (const float*)d_in[i++];
  P.to2_w     = (const float*)d_in[i++];
  P.to2_b     = (const float*)d_in[i++];
  P.n2_ln_g   = (const float*)d_in[i++];
  P.n2_ln_b   = (const float*)d_in[i++];
  P.n2_w1     = (const float*)d_in[i++];
  P.n2_b1     = (const float*)d_in[i++];
  P.n2_w2     = (const float*)d_in[i++];
  P.n2_b2     = (const float*)d_in[i++];
  P.brdf_ln_g = (const float*)d_in[i++];
  P.brdf_ln_b = (const float*)d_in[i++];
  P.brdf_w1   = (const float*)d_in[i++];
  P.brdf_b1   = (const float*)d_in[i++];
  P.brdf_w2   = (const float*)d_in[i++];
  P.brdf_b2   = (const float*)d_in[i++];
  P.out       = (float*)d_out;

  MultiViewAggregation_41300405518369_kernel<<<dim3(NBLK), dim3(NTHR), 0, stream>>>(P);
}